// Round 6
// baseline (380.428 us; speedup 1.0000x reference)
//
// Round-6: dispatch-count reduction. Proven inner loops untouched.
// 5 dispatches: prep -> mega1(g1+batch sk/ck) -> g2 -> lo_chain(g3,g4,task) -> final.
#include <hip/hip_runtime.h>
#include <hip/hip_bf16.h>
#include <math.h>

#define BNEPS 1e-5f
#define BDIM_B 128
#define CDIM 512
#define SS 121
#define KK 9
#define MROWS (BDIM_B * SS)   // 15488

typedef unsigned short u16;
typedef __bf16 bf16x8 __attribute__((ext_vector_type(8)));
typedef float f32x4 __attribute__((ext_vector_type(4)));

__device__ __forceinline__ u16 f2bf(float f) {
    union { float f; unsigned int u; } v; v.f = f;
    unsigned int r = v.u + 0x7FFF + ((v.u >> 16) & 1);   // RNE
    return (u16)(r >> 16);
}
__device__ __forceinline__ float bf2f(u16 v) {
    union { unsigned int u; float f; } x; x.u = ((unsigned int)v) << 16; return x.f;
}

__device__ __forceinline__ void gld16(const u16* g, u16* l) {
    __builtin_amdgcn_global_load_lds(
        (const __attribute__((address_space(1))) void*)g,
        (__attribute__((address_space(3))) void*)l, 16, 0, 0);
}

// ---------------------------------------------------------------------------
// 128x128 BK=64 MFMA GEMM body (round-0 proven: 49.6us @K=1024 grid 968).
// MODE 1: relu -> bf16, p-major remap Y[(m%121)*128 + m/121][n]
// MODE 2: block rows all one p (= bx); relu, reduce 128 rows -> bf16
// ---------------------------------------------------------------------------
template<int MODE>
__device__ __forceinline__ void gemm128_body(
    const u16* __restrict__ A, const u16* __restrict__ Bw,
    const float* __restrict__ bias, const float* __restrict__ g,
    const float* __restrict__ bb, void* __restrict__ out,
    int Kd, int N, int bi)
{
    __shared__ __align__(16) u16 Als[2][128 * 32];
    __shared__ __align__(16) u16 Bls[2][128 * 32];

    const int tid  = threadIdx.x;
    const int lane = tid & 63;
    const int w    = tid >> 6;
    const int wm   = w >> 1, wn = w & 1;

    int bx, by;
    {
        int i = bi;
        if (i < 960) {
            int xg = i & 7;
            int j  = i >> 3;
            bx = xg * 15 + (j >> 3);
            by = j & 7;
        } else { bx = 120; by = i - 960; }
    }
    const int bm = bx * 128;
    const int bn = by * 128;

    f32x4 acc[4][4] = {};

    const int subrow = tid >> 2;
    const int kq     = tid & 3;
    const int gchunk = kq ^ ((subrow >> 1) & 3);
    const u16* Ab = A  + (size_t)(bm + subrow) * Kd + gchunk * 8;
    const u16* Bb = Bw + (size_t)(bn + subrow) * Kd + gchunk * 8;
    u16* Al0  = &Als[0][(w * 16) * 32];
    u16* Al1  = &Als[0][(w * 16 + 64) * 32];
    u16* Bl0  = &Bls[0][(w * 16) * 32];
    u16* Bl1  = &Bls[0][(w * 16 + 64) * 32];
    u16* Al0b = &Als[1][(w * 16) * 32];
    u16* Al1b = &Als[1][(w * 16 + 64) * 32];
    u16* Bl0b = &Bls[1][(w * 16) * 32];
    u16* Bl1b = &Bls[1][(w * 16 + 64) * 32];

    const int fa_row = wm * 64 + (lane & 15);
    const int fb_row = wn * 64 + (lane & 15);
    const int kofs   = (((lane >> 4) ^ (((lane & 15) >> 1) & 3))) * 8;

    for (int k0 = 0; k0 < Kd; k0 += 64) {
        __syncthreads();
        gld16(Ab + k0,                      Al0);
        gld16(Ab + (size_t)64 * Kd + k0,    Al1);
        gld16(Bb + k0,                      Bl0);
        gld16(Bb + (size_t)64 * Kd + k0,    Bl1);
        gld16(Ab + k0 + 32,                 Al0b);
        gld16(Ab + (size_t)64 * Kd + k0 + 32, Al1b);
        gld16(Bb + k0 + 32,                 Bl0b);
        gld16(Bb + (size_t)64 * Kd + k0 + 32, Bl1b);
        __syncthreads();

        #pragma unroll
        for (int hb = 0; hb < 2; ++hb) {
            const u16* Ah = &Als[hb][0];
            const u16* Bh = &Bls[hb][0];
            bf16x8 af[4], bfv[4];
            #pragma unroll
            for (int i = 0; i < 4; ++i)
                af[i] = *(const bf16x8*)&Ah[(fa_row + i * 16) * 32 + kofs];
            #pragma unroll
            for (int j = 0; j < 4; ++j)
                bfv[j] = *(const bf16x8*)&Bh[(fb_row + j * 16) * 32 + kofs];
            #pragma unroll
            for (int i = 0; i < 4; ++i)
                #pragma unroll
                for (int j = 0; j < 4; ++j)
                    acc[i][j] = __builtin_amdgcn_mfma_f32_16x16x32_bf16(af[i], bfv[j], acc[i][j], 0, 0, 0);
        }
    }

    const float inv = 1.0f / sqrtf(1.0f + BNEPS);

    if (MODE == 1) {
        u16* Y = (u16*)out;
        int dstrow[4][4];
        #pragma unroll
        for (int i = 0; i < 4; ++i) {
            int mb = bm + wm * 64 + i * 16 + (lane >> 4) * 4;
            #pragma unroll
            for (int r = 0; r < 4; ++r) {
                int m = mb + r;
                int b = m / 121, p = m - b * 121;
                dstrow[i][r] = p * 128 + b;
            }
        }
        #pragma unroll
        for (int j = 0; j < 4; ++j) {
            int n = bn + wn * 64 + j * 16 + (lane & 15);
            float sc = g[n] * inv, bo = bias[n], bv = bb[n];
            #pragma unroll
            for (int i = 0; i < 4; ++i)
                #pragma unroll
                for (int r = 0; r < 4; ++r) {
                    float v = (acc[i][j][r] + bo) * sc + bv;
                    v = fmaxf(v, 0.0f);
                    Y[(size_t)dstrow[i][r] * N + n] = f2bf(v);
                }
        }
    } else {
        float ps[4];
        #pragma unroll
        for (int j = 0; j < 4; ++j) {
            int n = bn + wn * 64 + j * 16 + (lane & 15);
            float sc = g[n] * inv, bo = bias[n], bv = bb[n];
            float s = 0.f;
            #pragma unroll
            for (int i = 0; i < 4; ++i)
                #pragma unroll
                for (int r = 0; r < 4; ++r) {
                    float v = (acc[i][j][r] + bo) * sc + bv;
                    s += fmaxf(v, 0.0f);
                }
            ps[j] = s;
        }
        __syncthreads();
        float* red = (float*)Als;
        #pragma unroll
        for (int j = 0; j < 4; ++j)
            red[(wm * 4 + (lane >> 4)) * 128 + wn * 64 + j * 16 + (lane & 15)] = ps[j];
        __syncthreads();
        if (tid < 128) {
            float s = 0.f;
            #pragma unroll
            for (int r = 0; r < 8; ++r) s += red[r * 128 + tid];
            ((u16*)out)[(size_t)bx * N + bn + tid] = f2bf(s);
        }
    }
}

// ---------------------------------------------------------------------------
// barrier-free small GEMM body (M=128, proven round 4/5).
// MODE 3: relu; MODE 4: sigmoid. Y[m*N+n] bf16.
// ---------------------------------------------------------------------------
template<int MODE>
__device__ __forceinline__ void gemm_small_body(
    const u16* __restrict__ A, const u16* __restrict__ Bw,
    const float* __restrict__ bias, const float* __restrict__ g,
    const float* __restrict__ bb, u16* __restrict__ Y,
    int Kd, int N, int bn)
{
    const int tid  = threadIdx.x;
    const int lane = tid & 63;
    const int w    = tid >> 6;
    const int fr   = lane & 15;
    const int kq   = lane >> 4;
    const int r0   = w * 32;

    f32x4 acc[2][4] = {};
    const u16* a0p = A + (size_t)(r0 + fr) * Kd + kq * 8;
    const u16* a1p = a0p + (size_t)16 * Kd;
    const u16* bp  = Bw + (size_t)(bn + fr) * Kd + kq * 8;

    #pragma unroll 4
    for (int k0 = 0; k0 < Kd; k0 += 32) {
        bf16x8 a0 = *(const bf16x8*)(a0p + k0);
        bf16x8 a1 = *(const bf16x8*)(a1p + k0);
        #pragma unroll
        for (int j = 0; j < 4; ++j) {
            bf16x8 bv = *(const bf16x8*)(bp + (size_t)j * 16 * Kd + k0);
            acc[0][j] = __builtin_amdgcn_mfma_f32_16x16x32_bf16(a0, bv, acc[0][j], 0, 0, 0);
            acc[1][j] = __builtin_amdgcn_mfma_f32_16x16x32_bf16(a1, bv, acc[1][j], 0, 0, 0);
        }
    }

    const float inv = 1.0f / sqrtf(1.0f + BNEPS);
    #pragma unroll
    for (int j = 0; j < 4; ++j) {
        int n = bn + j * 16 + (lane & 15);
        float sc = g[n] * inv, bo = bias[n], bv = bb[n];
        #pragma unroll
        for (int t = 0; t < 2; ++t)
            #pragma unroll
            for (int r = 0; r < 4; ++r) {
                int m = r0 + t * 16 + (lane >> 4) * 4 + r;
                float v = (acc[t][j][r] + bo) * sc + bv;
                if (MODE == 3) v = fmaxf(v, 0.0f);
                else           v = 1.f / (1.f + expf(-v));
                Y[(size_t)m * N + n] = f2bf(v);
            }
    }
}

// ---------------------------------------------------------------------------
// spatial kernel body (proven): 128-row MFMA GEMM vs wcb (16x512, L1-hot).
// ---------------------------------------------------------------------------
__device__ __forceinline__ void spatial_body(
    const u16* __restrict__ Arow, const u16* __restrict__ wcb,
    const float* __restrict__ b_conv, const float* __restrict__ g_sp,
    const float* __restrict__ b_sp, float* __restrict__ skb,
    bool task, int blk, float* __restrict__ skt)
{
    const float inv = 1.0f / sqrtf(1.0f + BNEPS);
    const int lane = threadIdx.x & 63;
    const int w    = threadIdx.x >> 6;
    const int fr   = lane & 15;
    const int kq   = lane >> 4;
    const int r0   = w * 32;

    f32x4 acc0 = {}, acc1 = {};
    const u16* a0p = Arow + (size_t)(r0 + fr) * 512 + kq * 8;
    const u16* a1p = a0p + (size_t)16 * 512;
    const u16* bp  = wcb + (size_t)fr * 512 + kq * 8;
    #pragma unroll
    for (int k0 = 0; k0 < 512; k0 += 32) {
        bf16x8 a0 = *(const bf16x8*)(a0p + k0);
        bf16x8 a1 = *(const bf16x8*)(a1p + k0);
        bf16x8 b  = *(const bf16x8*)(bp + k0);
        acc0 = __builtin_amdgcn_mfma_f32_16x16x32_bf16(a0, b, acc0, 0, 0, 0);
        acc1 = __builtin_amdgcn_mfma_f32_16x16x32_bf16(a1, b, acc1, 0, 0, 0);
    }

    int n = lane & 15;
    if (n < 9) {
        float bo = b_conv[n];
        #pragma unroll
        for (int t = 0; t < 2; ++t) {
            f32x4 a = t ? acc1 : acc0;
            #pragma unroll
            for (int r = 0; r < 4; ++r) {
                int mloc = r0 + t * 16 + (lane >> 4) * 4 + r;
                if (!task) {
                    int m = blk * 128 + mloc;
                    int p = m % 121;
                    float v = (a[r] + bo) * (g_sp[p] * inv) + b_sp[p];
                    skb[(size_t)m * 9 + n] = v;
                } else if (mloc < 121) {
                    float v = (a[r] + bo) * (g_sp[mloc] * inv) + b_sp[mloc];
                    skt[(size_t)mloc * 9 + n] = v;
                }
            }
        }
    }
}

// ---------------------------------------------------------------------------
// channel chain body (proven): DCT pool (2c/thread) -> fc1 -> fc2+sig+BN.
// ---------------------------------------------------------------------------
__device__ __forceinline__ void channel_body(
    const u16* __restrict__ src, const float* __restrict__ dctT,
    const float* __restrict__ fc1, const float* __restrict__ fc2,
    const float* __restrict__ g_ch, const float* __restrict__ b_ch,
    float* __restrict__ outp, float* yls, float* y2ls)
{
    const float inv = 1.0f / sqrtf(1.0f + BNEPS);

    {
        int c = threadIdx.x * 2;
        float s0 = 0.f, s1 = 0.f;
        for (int p = 0; p < SS; ++p) {
            unsigned v = *(const unsigned*)(src + (size_t)p * 512 + c);
            float2 d  = *(const float2*)(dctT + (size_t)p * 512 + c);
            s0 += bf2f((u16)(v & 0xFFFFu)) * d.x;
            s1 += bf2f((u16)(v >> 16)) * d.y;
        }
        yls[c] = s0; yls[c + 1] = s1;
    }
    __syncthreads();

    {
        int o = threadIdx.x >> 3, kp = threadIdx.x & 7;
        const float* w = fc1 + (size_t)o * 512;
        float s = 0.f;
        for (int k = kp * 4; k < 512; k += 32) {
            float4 wv = *(const float4*)(w + k);
            float4 av = *(const float4*)(yls + k);
            s += wv.x * av.x + wv.y * av.y + wv.z * av.z + wv.w * av.w;
        }
        s += __shfl_xor(s, 1);
        s += __shfl_xor(s, 2);
        s += __shfl_xor(s, 4);
        if (kp == 0) y2ls[o] = fmaxf(s, 0.f);
    }
    __syncthreads();

    for (int o = threadIdx.x; o < CDIM * KK; o += 256) {
        const float* w = fc2 + (size_t)o * 32;
        float s = 0.f;
        #pragma unroll
        for (int k = 0; k < 32; ++k) s += y2ls[k] * w[k];
        s = 1.f / (1.f + expf(-s));
        int c = o / KK;
        s = s * (g_ch[c] * inv) + b_ch[c];
        outp[o] = s;
    }
}

// ---------------------------------------------------------------------------
// g1 GEMM standalone kernel (MODE 2 used for g2)
// ---------------------------------------------------------------------------
template<int MODE>
__global__ __launch_bounds__(256)
void gemm_mfma(const u16* __restrict__ A, const u16* __restrict__ Bw,
               const float* __restrict__ bias, const float* __restrict__ g,
               const float* __restrict__ bb, void* __restrict__ out,
               int Kd, int N)
{
    gemm128_body<MODE>(A, Bw, bias, g, bb, out, Kd, N, blockIdx.x);
}

// ---------------------------------------------------------------------------
// mega1: blocks [0,968): g1 GEMM (Xb @ w1b -> Y1, MODE 1)
//        blocks [968,1089): batch spatial (Xb -> skb)
//        blocks [1089,1217): batch channel (Xb -> ckbuf)
// all depend only on prep; sk/ck fills CUs behind the GEMM.
// ---------------------------------------------------------------------------
__global__ __launch_bounds__(256)
void mega1(const u16* __restrict__ Xb, const u16* __restrict__ w1b,
           const float* __restrict__ up_b1, const float* __restrict__ up_g1,
           const float* __restrict__ up_bb1, u16* __restrict__ Y1,
           const u16* __restrict__ wcb, const float* __restrict__ b_conv,
           const float* __restrict__ g_sp, const float* __restrict__ b_sp,
           const float* __restrict__ dctT,
           const float* __restrict__ fc1, const float* __restrict__ fc2,
           const float* __restrict__ g_ch, const float* __restrict__ b_ch,
           float* __restrict__ skb, float* __restrict__ ckbuf)
{
    __shared__ float sm[544];
    int bi = blockIdx.x;
    if (bi < 968) {
        gemm128_body<1>(Xb, w1b, up_b1, up_g1, up_bb1, (void*)Y1, 512, 1024, bi);
        return;
    }
    bi -= 968;
    if (bi < 121) {
        spatial_body(Xb + (size_t)bi * 128 * 512, wcb, b_conv, g_sp, b_sp,
                     skb, false, bi, nullptr);
        return;
    }
    bi -= 121;   // 0..127
    channel_body(Xb + (size_t)bi * 121 * 512, dctT, fc1, fc2, g_ch, b_ch,
                 ckbuf + (size_t)bi * CDIM * KK, sm, sm + 512);
}

// ---------------------------------------------------------------------------
// lo_chain: 16 blocks, 3 phases separated by device-scope spin barriers.
//   phase1: g3 = relu(asum_b @ lw1b) -> a3b    (16 blocks x 64 cols)
//   phase2: g4 = sigmoid(a3b @ lw2b) -> ts_pc  (8 blocks)
//   phase3: task spatial (block 0), task channel (block 1)
// 16 blocks trivially co-resident on 256 CUs; bar zeroed by prep each iter.
// ---------------------------------------------------------------------------
__device__ __forceinline__ void gbar(int* bar, int target)
{
    __syncthreads();
    if (threadIdx.x == 0) {
        __threadfence();                 // release my phase's writes
        atomicAdd(bar, 1);               // device-scope by default
        while (atomicAdd(bar, 0) < target) { }
        __threadfence();                 // acquire others' writes
    }
    __syncthreads();
}

__global__ __launch_bounds__(256)
void lo_chain(const u16* __restrict__ asum_b, const u16* __restrict__ lw1b,
              const float* __restrict__ lo_b1, const float* __restrict__ lo_g1,
              const float* __restrict__ lo_bb1, u16* __restrict__ a3b,
              const u16* __restrict__ lw2b,
              const float* __restrict__ lo_b2, const float* __restrict__ lo_g2,
              const float* __restrict__ lo_bb2, u16* __restrict__ ts_pc,
              const u16* __restrict__ wcb, const float* __restrict__ b_conv,
              const float* __restrict__ g_sp, const float* __restrict__ b_sp,
              const float* __restrict__ dctT,
              const float* __restrict__ fc1, const float* __restrict__ fc2,
              const float* __restrict__ g_ch, const float* __restrict__ b_ch,
              float* __restrict__ skt, float* __restrict__ ck_t,
              int* __restrict__ bar)
{
    __shared__ float sm[544];

    // phase 1: g3 (relu)
    gemm_small_body<3>(asum_b, lw1b, lo_b1, lo_g1, lo_bb1, a3b, 1024, 1024,
                       blockIdx.x * 64);
    gbar(bar, 16);

    // phase 2: g4 (sigmoid), 8 blocks
    if (blockIdx.x < 8)
        gemm_small_body<4>(a3b, lw2b, lo_b2, lo_g2, lo_bb2, ts_pc, 1024, 512,
                           blockIdx.x * 64);
    gbar(bar, 32);

    // phase 3: task spatial + channel
    if (blockIdx.x == 0)
        spatial_body(ts_pc, wcb, b_conv, g_sp, b_sp, nullptr, true, 0, skt);
    else if (blockIdx.x == 1)
        channel_body(ts_pc, dctT, fc1, fc2, g_ch, b_ch, ck_t, sm, sm + 512);
}

// ---------------------------------------------------------------------------
// prep combo: blocks [0,1024): x transpose -> Xb bf16
//   then vectorized weight casts, dct transpose, w_conv pad; zeros bar.
// ---------------------------------------------------------------------------
#define W1N (1024 * 512)
#define W2N (1024 * 1024)
#define L1N (1024 * 1024)
#define L2N (512 * 1024)
#define VECN ((W1N + W2N + L1N + L2N) / 4)   // 786432 quads
#define DCTN (512 * 121)
#define WCN (16 * 512)
#define PREP_ELEM (VECN + DCTN + WCN)
#define PREP_BLKS (1024 + (PREP_ELEM + 255) / 256)
__global__ void prep_combo(const float* __restrict__ x, u16* __restrict__ Xb,
                           const float* __restrict__ w1, const float* __restrict__ w2,
                           const float* __restrict__ l1, const float* __restrict__ l2,
                           const float* __restrict__ dct, const float* __restrict__ w_conv,
                           u16* __restrict__ o1, u16* __restrict__ o2,
                           u16* __restrict__ o3, u16* __restrict__ o4,
                           float* __restrict__ dctT, u16* __restrict__ wcb,
                           int* __restrict__ bar)
{
    __shared__ float t[64 * 121];
    if (blockIdx.x == 0 && threadIdx.x == 0) *bar = 0;   // reset lo_chain barrier
    if (blockIdx.x < 1024) {
        int b = blockIdx.x >> 3, c0 = (blockIdx.x & 7) * 64;
        for (int idx = threadIdx.x; idx < 64 * 121; idx += 256) {
            int c = idx / 121, p = idx - c * 121;
            t[idx] = x[((size_t)b * 512 + c0 + c) * 121 + p];
        }
        __syncthreads();
        for (int idx = threadIdx.x; idx < 121 * 64; idx += 256) {
            int p = idx >> 6, c = idx & 63;
            Xb[((size_t)(b * 121 + p)) * 512 + c0 + c] = f2bf(t[c * 121 + p]);
        }
        return;
    }
    int i = (blockIdx.x - 1024) * 256 + threadIdx.x;
    if (i < VECN) {
        int q = i;
        const float* s; u16* d;
        if (q < W1N / 4)                    { s = w1; d = o1; }
        else if (q < (W1N + W2N) / 4)       { s = w2; d = o2; q -= W1N / 4; }
        else if (q < (W1N + W2N + L1N) / 4) { s = l1; d = o3; q -= (W1N + W2N) / 4; }
        else                                { s = l2; d = o4; q -= (W1N + W2N + L1N) / 4; }
        float4 v = ((const float4*)s)[q];
        uint2 r;
        r.x = (unsigned)f2bf(v.x) | ((unsigned)f2bf(v.y) << 16);
        r.y = (unsigned)f2bf(v.z) | ((unsigned)f2bf(v.w) << 16);
        ((uint2*)d)[q] = r;
        return;
    }
    i -= VECN;
    if (i < DCTN) {
        int p = i >> 9, c = i & 511;
        dctT[i] = dct[(size_t)c * 121 + p];
        return;
    }
    i -= DCTN;
    if (i < WCN) {
        int n = i >> 9, c = i & 511;
        wcb[i] = (n < 9) ? f2bf(w_conv[(size_t)n * 512 + c]) : (u16)0;
    }
}

// ---------------------------------------------------------------------------
// final combo (vectorized, proven):
// blocks [0,1024): out0[b,c,p] = (1/9) sum_k unfold(x)[k]*PS[p,k]*CS[c,k] + x
// blocks [1024,..): tk write
// ---------------------------------------------------------------------------
#define TKN (CDIM * SS * KK)              // 557568
#define FIN_BLKS (1024 + (TKN + 255) / 256)
__global__ __launch_bounds__(256)
void final_combo(const float* __restrict__ x, const float* __restrict__ skb,
                 const float* __restrict__ sk_t, const float* __restrict__ ckbuf,
                 const float* __restrict__ ck_t, float* __restrict__ out0,
                 float* __restrict__ tk)
{
    __shared__ float PS[SS * KK];
    __shared__ float CS[64 * KK];
    __shared__ float XT[64 * SS];

    if (blockIdx.x >= 1024) {
        int idx = (blockIdx.x - 1024) * 256 + threadIdx.x;
        if (idx < TKN) {
            int k9 = idx % KK;
            int pc = idx / KK;
            int p = pc % SS, c = pc / SS;
            tk[idx] = sk_t[p * KK + k9] * ck_t[c * KK + k9];
        }
        return;
    }

    const int tid = threadIdx.x;
    const int b = blockIdx.x >> 3, c0 = (blockIdx.x & 7) * 64;

    const float* sp = skb + (size_t)b * SS * KK;
    for (int i = tid; i < SS * KK; i += 256) PS[i] = sp[i] * sk_t[i];
    const float* cp = ckbuf + ((size_t)b * CDIM + c0) * KK;
    const float* tp = ck_t + (size_t)c0 * KK;
    for (int i = tid; i < (64 * KK) / 4; i += 256) {
        float4 a = ((const float4*)cp)[i];
        float4 bq = ((const float4*)tp)[i];
        float4 r; r.x = a.x * bq.x; r.y = a.y * bq.y; r.z = a.z * bq.z; r.w = a.w * bq.w;
        ((float4*)CS)[i] = r;
    }
    const float* xp = x + ((size_t)b * CDIM + c0) * SS;
    for (int i = tid; i < (64 * SS) / 4; i += 256)
        ((float4*)XT)[i] = ((const float4*)xp)[i];
    __syncthreads();

    float* op = out0 + ((size_t)b * CDIM + c0) * SS;
    for (int ci = tid; ci < (64 * SS) / 4; ci += 256) {
        float4 o;
        #pragma unroll
        for (int r = 0; r < 4; ++r) {
            int i = ci * 4 + r;
            int c = i / SS, p = i - c * SS;
            int h = p / 11, w = p - h * 11;
            const float* xc = XT + c * SS;
            const float* ps = PS + p * KK;
            const float* cs = CS + c * KK;
            float acc = 0.f;
            #pragma unroll
            for (int di = 0; di < 3; ++di) {
                int hh = h + di - 1;
                bool hv = (unsigned)hh < 11u;
                #pragma unroll
                for (int dj = 0; dj < 3; ++dj) {
                    int ww = w + dj - 1;
                    int k = di * 3 + dj;
                    float xv = (hv && (unsigned)ww < 11u) ? xc[hh * 11 + ww] : 0.f;
                    acc += xv * ps[k] * cs[k];
                }
            }
            ((float*)&o)[r] = acc * (1.0f / 9.0f) + xc[p];
        }
        ((float4*)op)[ci] = o;
    }
}

extern "C" void kernel_launch(void* const* d_in, const int* in_sizes, int n_in,
                              void* d_out, int out_size, void* d_ws, size_t ws_size,
                              hipStream_t stream)
{
    const float* x      = (const float*)d_in[0];
    const float* dct_w  = (const float*)d_in[1];
    const float* w_conv = (const float*)d_in[2];
    const float* b_conv = (const float*)d_in[3];
    const float* g_sp   = (const float*)d_in[4];
    const float* b_sp   = (const float*)d_in[5];
    const float* g_ch   = (const float*)d_in[6];
    const float* b_ch   = (const float*)d_in[7];
    const float* fc1    = (const float*)d_in[8];
    const float* fc2    = (const float*)d_in[9];
    const float* up_w1  = (const float*)d_in[10];
    const float* up_b1  = (const float*)d_in[11];
    const float* up_g1  = (const float*)d_in[12];
    const float* up_bb1 = (const float*)d_in[13];
    const float* up_w2  = (const float*)d_in[14];
    const float* up_b2  = (const float*)d_in[15];
    const float* up_g2  = (const float*)d_in[16];
    const float* up_bb2 = (const float*)d_in[17];
    const float* lo_w1  = (const float*)d_in[18];
    const float* lo_b1  = (const float*)d_in[19];
    const float* lo_g1  = (const float*)d_in[20];
    const float* lo_bb1 = (const float*)d_in[21];
    const float* lo_w2  = (const float*)d_in[22];
    const float* lo_b2  = (const float*)d_in[23];
    const float* lo_g2  = (const float*)d_in[24];
    const float* lo_bb2 = (const float*)d_in[25];

    float* out0 = (float*)d_out;                       // (B,C,11,11)
    float* tk   = out0 + (size_t)BDIM_B * CDIM * SS;   // (1,C,11,11,3,3)

    // workspace layout (bytes, 64B-aligned chunks)
    char* ws = (char*)d_ws;
    size_t off = 0;
    auto alloc = [&](size_t bytes) { void* p = ws + off; off += (bytes + 63) & ~(size_t)63; return p; };
    u16*   Xb      = (u16*)alloc((size_t)MROWS * 512 * 2);
    u16*   Y1      = (u16*)alloc((size_t)MROWS * 1024 * 2);
    u16*   w1b     = (u16*)alloc((size_t)W1N * 2);
    u16*   w2b     = (u16*)alloc((size_t)W2N * 2);
    u16*   lw1b    = (u16*)alloc((size_t)L1N * 2);
    u16*   lw2b    = (u16*)alloc((size_t)L2N * 2);
    u16*   asum_b  = (u16*)alloc((size_t)128 * 1024 * 2);   // rows 121..127 unwritten
    u16*   a3b     = (u16*)alloc((size_t)128 * 1024 * 2);
    u16*   ts_pc   = (u16*)alloc((size_t)128 * 512 * 2);    // task_s (p,c) bf16
    float* dctT    = (float*)alloc((size_t)SS * 512 * 4);
    u16*   wcb     = (u16*)alloc((size_t)WCN * 2);          // w_conv bf16 16x512 (pad)
    float* ckbuf   = (float*)alloc((size_t)BDIM_B * CDIM * KK * 4);
    float* skbuf   = (float*)alloc((size_t)BDIM_B * SS * KK * 4);
    float* ck_t    = (float*)alloc((size_t)CDIM * KK * 4);
    float* sk_t    = (float*)alloc((size_t)SS * KK * 4);
    int*   bar     = (int*)alloc(64);

    // --- 1. prep: x transpose + weight casts + dct transpose + bar reset ---
    hipLaunchKernelGGL(prep_combo, dim3(PREP_BLKS), dim3(256), 0, stream,
                       x, Xb, up_w1, up_w2, lo_w1, lo_w2, dct_w, w_conv,
                       w1b, w2b, lw1b, lw2b, dctT, wcb, bar);

    // --- 2. mega1: g1 GEMM + batch spatial + batch channel (1217 blocks) ---
    hipLaunchKernelGGL(mega1, dim3(968 + 121 + 128), dim3(256), 0, stream,
                       Xb, w1b, up_b1, up_g1, up_bb1, Y1,
                       wcb, b_conv, g_sp, b_sp,
                       dctT, fc1, fc2, g_ch, b_ch,
                       skbuf, ckbuf);

    // --- 3. g2: batch-reduced GEMM (round-0 BK=64 structure) ---
    hipLaunchKernelGGL((gemm_mfma<2>), dim3(121 * 8), dim3(256), 0, stream,
                       Y1, w2b, up_b2, up_g2, up_bb2, (void*)asum_b, 1024, 1024);

    // --- 4. lo_chain: g3 -> g4 -> task sk/ck, one 16-block dispatch ---
    hipLaunchKernelGGL(lo_chain, dim3(16), dim3(256), 0, stream,
                       asum_b, lw1b, lo_b1, lo_g1, lo_bb1, a3b,
                       lw2b, lo_b2, lo_g2, lo_bb2, ts_pc,
                       wcb, b_conv, g_sp, b_sp,
                       dctT, fc1, fc2, g_ch, b_ch,
                       sk_t, ck_t, bar);

    // --- 5. final fused + task-kernel write ---
    hipLaunchKernelGGL(final_combo, dim3(FIN_BLKS), dim3(256), 0, stream,
                       x, skbuf, sk_t, ckbuf, ck_t, out0, tk);
}

// Round 7
// 316.585 us; speedup vs baseline: 1.2017x; 1.2017x over previous
//
// Round-7: round-5 proven base; ONLY change = gemm_small re-tiled to 32-col
// blocks (g3: 32 blocks, g4: 16 blocks) for latency-bound parallelism.
#include <hip/hip_runtime.h>
#include <hip/hip_bf16.h>
#include <math.h>

#define BNEPS 1e-5f
#define BDIM_B 128
#define CDIM 512
#define SS 121
#define KK 9
#define MROWS (BDIM_B * SS)   // 15488

typedef unsigned short u16;
typedef __bf16 bf16x8 __attribute__((ext_vector_type(8)));
typedef float f32x4 __attribute__((ext_vector_type(4)));

__device__ __forceinline__ u16 f2bf(float f) {
    union { float f; unsigned int u; } v; v.f = f;
    unsigned int r = v.u + 0x7FFF + ((v.u >> 16) & 1);   // RNE
    return (u16)(r >> 16);
}
__device__ __forceinline__ float bf2f(u16 v) {
    union { unsigned int u; float f; } x; x.u = ((unsigned int)v) << 16; return x.f;
}

__device__ __forceinline__ void gld16(const u16* g, u16* l) {
    __builtin_amdgcn_global_load_lds(
        (const __attribute__((address_space(1))) void*)g,
        (__attribute__((address_space(3))) void*)l, 16, 0, 0);
}

// ---------------------------------------------------------------------------
// bf16 MFMA GEMM, 128x128 tile, BK=64 (32 MFMA between barriers) — round-0
// proven structure (49.6 us @ K=1024 grid 968).
// SWIZ=1 (grid 968): XCD g (=blockIdx%8) owns M-chunk -> L2-resident panels.
// MODE 1: relu -> bf16, p-major remap. MODE 2: relu + 128-row batch reduce.
// ---------------------------------------------------------------------------
template<int MODE, int SWIZ>
__global__ __launch_bounds__(256)
void gemm_mfma(const u16* __restrict__ A, const u16* __restrict__ Bw,
               const float* __restrict__ bias, const float* __restrict__ g,
               const float* __restrict__ bb, void* __restrict__ out,
               int Kd, int N, int NT)
{
    __shared__ __align__(16) u16 Als[2][128 * 32];
    __shared__ __align__(16) u16 Bls[2][128 * 32];

    const int tid  = threadIdx.x;
    const int lane = tid & 63;
    const int w    = tid >> 6;
    const int wm   = w >> 1, wn = w & 1;

    int bx, by;
    if (SWIZ) {
        int i = blockIdx.x;
        if (i < 960) {
            int xg = i & 7;
            int j  = i >> 3;
            bx = xg * 15 + (j >> 3);
            by = j & 7;
        } else { bx = 120; by = i - 960; }
    } else {
        bx = blockIdx.x / NT; by = blockIdx.x - bx * NT;
    }
    const int bm = bx * 128;
    const int bn = by * 128;

    f32x4 acc[4][4] = {};

    const int subrow = tid >> 2;
    const int kq     = tid & 3;
    const int gchunk = kq ^ ((subrow >> 1) & 3);
    const u16* Ab = A  + (size_t)(bm + subrow) * Kd + gchunk * 8;
    const u16* Bb = Bw + (size_t)(bn + subrow) * Kd + gchunk * 8;
    u16* Al0  = &Als[0][(w * 16) * 32];
    u16* Al1  = &Als[0][(w * 16 + 64) * 32];
    u16* Bl0  = &Bls[0][(w * 16) * 32];
    u16* Bl1  = &Bls[0][(w * 16 + 64) * 32];
    u16* Al0b = &Als[1][(w * 16) * 32];
    u16* Al1b = &Als[1][(w * 16 + 64) * 32];
    u16* Bl0b = &Bls[1][(w * 16) * 32];
    u16* Bl1b = &Bls[1][(w * 16 + 64) * 32];

    const int fa_row = wm * 64 + (lane & 15);
    const int fb_row = wn * 64 + (lane & 15);
    const int kofs   = (((lane >> 4) ^ (((lane & 15) >> 1) & 3))) * 8;

    for (int k0 = 0; k0 < Kd; k0 += 64) {
        __syncthreads();
        gld16(Ab + k0,                      Al0);
        gld16(Ab + (size_t)64 * Kd + k0,    Al1);
        gld16(Bb + k0,                      Bl0);
        gld16(Bb + (size_t)64 * Kd + k0,    Bl1);
        gld16(Ab + k0 + 32,                 Al0b);
        gld16(Ab + (size_t)64 * Kd + k0 + 32, Al1b);
        gld16(Bb + k0 + 32,                 Bl0b);
        gld16(Bb + (size_t)64 * Kd + k0 + 32, Bl1b);
        __syncthreads();

        #pragma unroll
        for (int hb = 0; hb < 2; ++hb) {
            const u16* Ah = &Als[hb][0];
            const u16* Bh = &Bls[hb][0];
            bf16x8 af[4], bfv[4];
            #pragma unroll
            for (int i = 0; i < 4; ++i)
                af[i] = *(const bf16x8*)&Ah[(fa_row + i * 16) * 32 + kofs];
            #pragma unroll
            for (int j = 0; j < 4; ++j)
                bfv[j] = *(const bf16x8*)&Bh[(fb_row + j * 16) * 32 + kofs];
            #pragma unroll
            for (int i = 0; i < 4; ++i)
                #pragma unroll
                for (int j = 0; j < 4; ++j)
                    acc[i][j] = __builtin_amdgcn_mfma_f32_16x16x32_bf16(af[i], bfv[j], acc[i][j], 0, 0, 0);
        }
    }

    const float inv = 1.0f / sqrtf(1.0f + BNEPS);

    if (MODE == 1) {
        u16* Y = (u16*)out;
        int dstrow[4][4];
        #pragma unroll
        for (int i = 0; i < 4; ++i) {
            int mb = bm + wm * 64 + i * 16 + (lane >> 4) * 4;
            #pragma unroll
            for (int r = 0; r < 4; ++r) {
                int m = mb + r;
                int b = m / 121, p = m - b * 121;
                dstrow[i][r] = p * 128 + b;
            }
        }
        #pragma unroll
        for (int j = 0; j < 4; ++j) {
            int n = bn + wn * 64 + j * 16 + (lane & 15);
            float sc = g[n] * inv, bo = bias[n], bv = bb[n];
            #pragma unroll
            for (int i = 0; i < 4; ++i)
                #pragma unroll
                for (int r = 0; r < 4; ++r) {
                    float v = (acc[i][j][r] + bo) * sc + bv;
                    v = fmaxf(v, 0.0f);
                    Y[(size_t)dstrow[i][r] * N + n] = f2bf(v);
                }
        }
    } else {
        float ps[4];
        #pragma unroll
        for (int j = 0; j < 4; ++j) {
            int n = bn + wn * 64 + j * 16 + (lane & 15);
            float sc = g[n] * inv, bo = bias[n], bv = bb[n];
            float s = 0.f;
            #pragma unroll
            for (int i = 0; i < 4; ++i)
                #pragma unroll
                for (int r = 0; r < 4; ++r) {
                    float v = (acc[i][j][r] + bo) * sc + bv;
                    s += fmaxf(v, 0.0f);
                }
            ps[j] = s;
        }
        __syncthreads();
        float* red = (float*)Als;
        #pragma unroll
        for (int j = 0; j < 4; ++j)
            red[(wm * 4 + (lane >> 4)) * 128 + wn * 64 + j * 16 + (lane & 15)] = ps[j];
        __syncthreads();
        if (tid < 128) {
            float s = 0.f;
            #pragma unroll
            for (int r = 0; r < 8; ++r) s += red[r * 128 + tid];
            ((u16*)out)[(size_t)bx * N + bn + tid] = f2bf(s);
        }
    }
}

// ---------------------------------------------------------------------------
// barrier-free small GEMM (M=128), 32-col blocks: wave = 32 rows x 32 cols,
// acc[2][2]. Same per-element K-summation order as the proven 64-col body
// (bitwise-identical output); 2x the blocks for latency-bound CU coverage.
// MODE 3: relu; MODE 4: sigmoid. Y[m*N+n] bf16.
// ---------------------------------------------------------------------------
template<int MODE>
__global__ __launch_bounds__(256)
void gemm_small(const u16* __restrict__ A, const u16* __restrict__ Bw,
                const float* __restrict__ bias, const float* __restrict__ g,
                const float* __restrict__ bb, u16* __restrict__ Y,
                int Kd, int N)
{
    const int bn   = blockIdx.x * 32;
    const int tid  = threadIdx.x;
    const int lane = tid & 63;
    const int w    = tid >> 6;
    const int fr   = lane & 15;
    const int kq   = lane >> 4;
    const int r0   = w * 32;

    f32x4 acc[2][2] = {};
    const u16* a0p = A + (size_t)(r0 + fr) * Kd + kq * 8;
    const u16* a1p = a0p + (size_t)16 * Kd;
    const u16* b0p = Bw + (size_t)(bn + fr) * Kd + kq * 8;
    const u16* b1p = b0p + (size_t)16 * Kd;

    #pragma unroll 4
    for (int k0 = 0; k0 < Kd; k0 += 32) {
        bf16x8 a0 = *(const bf16x8*)(a0p + k0);
        bf16x8 a1 = *(const bf16x8*)(a1p + k0);
        bf16x8 b0 = *(const bf16x8*)(b0p + k0);
        bf16x8 b1 = *(const bf16x8*)(b1p + k0);
        acc[0][0] = __builtin_amdgcn_mfma_f32_16x16x32_bf16(a0, b0, acc[0][0], 0, 0, 0);
        acc[0][1] = __builtin_amdgcn_mfma_f32_16x16x32_bf16(a0, b1, acc[0][1], 0, 0, 0);
        acc[1][0] = __builtin_amdgcn_mfma_f32_16x16x32_bf16(a1, b0, acc[1][0], 0, 0, 0);
        acc[1][1] = __builtin_amdgcn_mfma_f32_16x16x32_bf16(a1, b1, acc[1][1], 0, 0, 0);
    }

    const float inv = 1.0f / sqrtf(1.0f + BNEPS);
    #pragma unroll
    for (int j = 0; j < 2; ++j) {
        int n = bn + j * 16 + (lane & 15);
        float sc = g[n] * inv, bo = bias[n], bv = bb[n];
        #pragma unroll
        for (int t = 0; t < 2; ++t)
            #pragma unroll
            for (int r = 0; r < 4; ++r) {
                int m = r0 + t * 16 + (lane >> 4) * 4 + r;
                float v = (acc[t][j][r] + bo) * sc + bv;
                if (MODE == 3) v = fmaxf(v, 0.0f);
                else           v = 1.f / (1.f + expf(-v));
                Y[(size_t)m * N + n] = f2bf(v);
            }
    }
}

// ---------------------------------------------------------------------------
// spatial kernel body (proven): 128-row MFMA GEMM vs wcb (16x512, L1-hot).
// ---------------------------------------------------------------------------
__device__ __forceinline__ void spatial_body(
    const u16* __restrict__ Arow, const u16* __restrict__ wcb,
    const float* __restrict__ b_conv, const float* __restrict__ g_sp,
    const float* __restrict__ b_sp, float* __restrict__ skb,
    bool task, int blk, float* __restrict__ skt)
{
    const float inv = 1.0f / sqrtf(1.0f + BNEPS);
    const int lane = threadIdx.x & 63;
    const int w    = threadIdx.x >> 6;
    const int fr   = lane & 15;
    const int kq   = lane >> 4;
    const int r0   = w * 32;

    f32x4 acc0 = {}, acc1 = {};
    const u16* a0p = Arow + (size_t)(r0 + fr) * 512 + kq * 8;
    const u16* a1p = a0p + (size_t)16 * 512;
    const u16* bp  = wcb + (size_t)fr * 512 + kq * 8;
    #pragma unroll
    for (int k0 = 0; k0 < 512; k0 += 32) {
        bf16x8 a0 = *(const bf16x8*)(a0p + k0);
        bf16x8 a1 = *(const bf16x8*)(a1p + k0);
        bf16x8 b  = *(const bf16x8*)(bp + k0);
        acc0 = __builtin_amdgcn_mfma_f32_16x16x32_bf16(a0, b, acc0, 0, 0, 0);
        acc1 = __builtin_amdgcn_mfma_f32_16x16x32_bf16(a1, b, acc1, 0, 0, 0);
    }

    int n = lane & 15;
    if (n < 9) {
        float bo = b_conv[n];
        #pragma unroll
        for (int t = 0; t < 2; ++t) {
            f32x4 a = t ? acc1 : acc0;
            #pragma unroll
            for (int r = 0; r < 4; ++r) {
                int mloc = r0 + t * 16 + (lane >> 4) * 4 + r;
                if (!task) {
                    int m = blk * 128 + mloc;
                    int p = m % 121;
                    float v = (a[r] + bo) * (g_sp[p] * inv) + b_sp[p];
                    skb[(size_t)m * 9 + n] = v;
                } else if (mloc < 121) {
                    float v = (a[r] + bo) * (g_sp[mloc] * inv) + b_sp[mloc];
                    skt[(size_t)mloc * 9 + n] = v;
                }
            }
        }
    }
}

// ---------------------------------------------------------------------------
// channel chain body (proven): DCT pool (2c/thread) -> fc1 -> fc2+sig+BN.
// ---------------------------------------------------------------------------
__device__ __forceinline__ void channel_body(
    const u16* __restrict__ src, const float* __restrict__ dctT,
    const float* __restrict__ fc1, const float* __restrict__ fc2,
    const float* __restrict__ g_ch, const float* __restrict__ b_ch,
    float* __restrict__ outp, float* yls, float* y2ls)
{
    const float inv = 1.0f / sqrtf(1.0f + BNEPS);

    {
        int c = threadIdx.x * 2;
        float s0 = 0.f, s1 = 0.f;
        for (int p = 0; p < SS; ++p) {
            unsigned v = *(const unsigned*)(src + (size_t)p * 512 + c);
            float2 d  = *(const float2*)(dctT + (size_t)p * 512 + c);
            s0 += bf2f((u16)(v & 0xFFFFu)) * d.x;
            s1 += bf2f((u16)(v >> 16)) * d.y;
        }
        yls[c] = s0; yls[c + 1] = s1;
    }
    __syncthreads();

    {
        int o = threadIdx.x >> 3, kp = threadIdx.x & 7;
        const float* w = fc1 + (size_t)o * 512;
        float s = 0.f;
        for (int k = kp * 4; k < 512; k += 32) {
            float4 wv = *(const float4*)(w + k);
            float4 av = *(const float4*)(yls + k);
            s += wv.x * av.x + wv.y * av.y + wv.z * av.z + wv.w * av.w;
        }
        s += __shfl_xor(s, 1);
        s += __shfl_xor(s, 2);
        s += __shfl_xor(s, 4);
        if (kp == 0) y2ls[o] = fmaxf(s, 0.f);
    }
    __syncthreads();

    for (int o = threadIdx.x; o < CDIM * KK; o += 256) {
        const float* w = fc2 + (size_t)o * 32;
        float s = 0.f;
        #pragma unroll
        for (int k = 0; k < 32; ++k) s += y2ls[k] * w[k];
        s = 1.f / (1.f + expf(-s));
        int c = o / KK;
        s = s * (g_ch[c] * inv) + b_ch[c];
        outp[o] = s;
    }
}

// ---------------------------------------------------------------------------
// spatial+channel, one 251-block dispatch (round-5 proven).
// ---------------------------------------------------------------------------
__global__ __launch_bounds__(256)
void spatial_ck_combo(const u16* __restrict__ Xb, const u16* __restrict__ Xt,
                      const u16* __restrict__ wcb, const float* __restrict__ b_conv,
                      const float* __restrict__ g_sp, const float* __restrict__ b_sp,
                      const float* __restrict__ dctT,
                      const float* __restrict__ fc1, const float* __restrict__ fc2,
                      const float* __restrict__ g_ch, const float* __restrict__ b_ch,
                      float* __restrict__ skb, float* __restrict__ skt,
                      float* __restrict__ ckbuf, float* __restrict__ ck_t)
{
    __shared__ float sm[544];
    if (blockIdx.x < 122) {
        const bool task = (blockIdx.x == 121);
        spatial_body(task ? Xt : Xb + (size_t)blockIdx.x * 128 * 512,
                     wcb, b_conv, g_sp, b_sp, skb, task, blockIdx.x, skt);
        return;
    }
    const int g = blockIdx.x - 122;                    // 0..128
    const u16* src = (g < 128) ? Xb + (size_t)g * 121 * 512 : Xt;
    channel_body(src, dctT, fc1, fc2, g_ch, b_ch,
                 (g < 128) ? ckbuf + (size_t)g * CDIM * KK : ck_t, sm, sm + 512);
}

// ---------------------------------------------------------------------------
// prep combo (proven): x transpose + vectorized weight casts + dct transpose
// + w_conv pad.
// ---------------------------------------------------------------------------
#define W1N (1024 * 512)
#define W2N (1024 * 1024)
#define L1N (1024 * 1024)
#define L2N (512 * 1024)
#define VECN ((W1N + W2N + L1N + L2N) / 4)   // 786432 quads
#define DCTN (512 * 121)
#define WCN (16 * 512)
#define PREP_ELEM (VECN + DCTN + WCN)
#define PREP_BLKS (1024 + (PREP_ELEM + 255) / 256)
__global__ void prep_combo(const float* __restrict__ x, u16* __restrict__ Xb,
                           const float* __restrict__ w1, const float* __restrict__ w2,
                           const float* __restrict__ l1, const float* __restrict__ l2,
                           const float* __restrict__ dct, const float* __restrict__ w_conv,
                           u16* __restrict__ o1, u16* __restrict__ o2,
                           u16* __restrict__ o3, u16* __restrict__ o4,
                           float* __restrict__ dctT, u16* __restrict__ wcb)
{
    __shared__ float t[64 * 121];
    if (blockIdx.x < 1024) {
        int b = blockIdx.x >> 3, c0 = (blockIdx.x & 7) * 64;
        for (int idx = threadIdx.x; idx < 64 * 121; idx += 256) {
            int c = idx / 121, p = idx - c * 121;
            t[idx] = x[((size_t)b * 512 + c0 + c) * 121 + p];
        }
        __syncthreads();
        for (int idx = threadIdx.x; idx < 121 * 64; idx += 256) {
            int p = idx >> 6, c = idx & 63;
            Xb[((size_t)(b * 121 + p)) * 512 + c0 + c] = f2bf(t[c * 121 + p]);
        }
        return;
    }
    int i = (blockIdx.x - 1024) * 256 + threadIdx.x;
    if (i < VECN) {
        int q = i;
        const float* s; u16* d;
        if (q < W1N / 4)                    { s = w1; d = o1; }
        else if (q < (W1N + W2N) / 4)       { s = w2; d = o2; q -= W1N / 4; }
        else if (q < (W1N + W2N + L1N) / 4) { s = l1; d = o3; q -= (W1N + W2N) / 4; }
        else                                { s = l2; d = o4; q -= (W1N + W2N + L1N) / 4; }
        float4 v = ((const float4*)s)[q];
        uint2 r;
        r.x = (unsigned)f2bf(v.x) | ((unsigned)f2bf(v.y) << 16);
        r.y = (unsigned)f2bf(v.z) | ((unsigned)f2bf(v.w) << 16);
        ((uint2*)d)[q] = r;
        return;
    }
    i -= VECN;
    if (i < DCTN) {
        int p = i >> 9, c = i & 511;
        dctT[i] = dct[(size_t)c * 121 + p];
        return;
    }
    i -= DCTN;
    if (i < WCN) {
        int n = i >> 9, c = i & 511;
        wcb[i] = (n < 9) ? f2bf(w_conv[(size_t)n * 512 + c]) : (u16)0;
    }
}

// ---------------------------------------------------------------------------
// final combo (vectorized, proven).
// ---------------------------------------------------------------------------
#define TKN (CDIM * SS * KK)              // 557568
#define FIN_BLKS (1024 + (TKN + 255) / 256)
__global__ __launch_bounds__(256)
void final_combo(const float* __restrict__ x, const float* __restrict__ skb,
                 const float* __restrict__ sk_t, const float* __restrict__ ckbuf,
                 const float* __restrict__ ck_t, float* __restrict__ out0,
                 float* __restrict__ tk)
{
    __shared__ float PS[SS * KK];
    __shared__ float CS[64 * KK];
    __shared__ float XT[64 * SS];

    if (blockIdx.x >= 1024) {
        int idx = (blockIdx.x - 1024) * 256 + threadIdx.x;
        if (idx < TKN) {
            int k9 = idx % KK;
            int pc = idx / KK;
            int p = pc % SS, c = pc / SS;
            tk[idx] = sk_t[p * KK + k9] * ck_t[c * KK + k9];
        }
        return;
    }

    const int tid = threadIdx.x;
    const int b = blockIdx.x >> 3, c0 = (blockIdx.x & 7) * 64;

    const float* sp = skb + (size_t)b * SS * KK;
    for (int i = tid; i < SS * KK; i += 256) PS[i] = sp[i] * sk_t[i];
    const float* cp = ckbuf + ((size_t)b * CDIM + c0) * KK;
    const float* tp = ck_t + (size_t)c0 * KK;
    for (int i = tid; i < (64 * KK) / 4; i += 256) {
        float4 a = ((const float4*)cp)[i];
        float4 bq = ((const float4*)tp)[i];
        float4 r; r.x = a.x * bq.x; r.y = a.y * bq.y; r.z = a.z * bq.z; r.w = a.w * bq.w;
        ((float4*)CS)[i] = r;
    }
    const float* xp = x + ((size_t)b * CDIM + c0) * SS;
    for (int i = tid; i < (64 * SS) / 4; i += 256)
        ((float4*)XT)[i] = ((const float4*)xp)[i];
    __syncthreads();

    float* op = out0 + ((size_t)b * CDIM + c0) * SS;
    for (int ci = tid; ci < (64 * SS) / 4; ci += 256) {
        float4 o;
        #pragma unroll
        for (int r = 0; r < 4; ++r) {
            int i = ci * 4 + r;
            int c = i / SS, p = i - c * SS;
            int h = p / 11, w = p - h * 11;
            const float* xc = XT + c * SS;
            const float* ps = PS + p * KK;
            const float* cs = CS + c * KK;
            float acc = 0.f;
            #pragma unroll
            for (int di = 0; di < 3; ++di) {
                int hh = h + di - 1;
                bool hv = (unsigned)hh < 11u;
                #pragma unroll
                for (int dj = 0; dj < 3; ++dj) {
                    int ww = w + dj - 1;
                    int k = di * 3 + dj;
                    float xv = (hv && (unsigned)ww < 11u) ? xc[hh * 11 + ww] : 0.f;
                    acc += xv * ps[k] * cs[k];
                }
            }
            ((float*)&o)[r] = acc * (1.0f / 9.0f) + xc[p];
        }
        ((float4*)op)[ci] = o;
    }
}

extern "C" void kernel_launch(void* const* d_in, const int* in_sizes, int n_in,
                              void* d_out, int out_size, void* d_ws, size_t ws_size,
                              hipStream_t stream)
{
    const float* x      = (const float*)d_in[0];
    const float* dct_w  = (const float*)d_in[1];
    const float* w_conv = (const float*)d_in[2];
    const float* b_conv = (const float*)d_in[3];
    const float* g_sp   = (const float*)d_in[4];
    const float* b_sp   = (const float*)d_in[5];
    const float* g_ch   = (const float*)d_in[6];
    const float* b_ch   = (const float*)d_in[7];
    const float* fc1    = (const float*)d_in[8];
    const float* fc2    = (const float*)d_in[9];
    const float* up_w1  = (const float*)d_in[10];
    const float* up_b1  = (const float*)d_in[11];
    const float* up_g1  = (const float*)d_in[12];
    const float* up_bb1 = (const float*)d_in[13];
    const float* up_w2  = (const float*)d_in[14];
    const float* up_b2  = (const float*)d_in[15];
    const float* up_g2  = (const float*)d_in[16];
    const float* up_bb2 = (const float*)d_in[17];
    const float* lo_w1  = (const float*)d_in[18];
    const float* lo_b1  = (const float*)d_in[19];
    const float* lo_g1  = (const float*)d_in[20];
    const float* lo_bb1 = (const float*)d_in[21];
    const float* lo_w2  = (const float*)d_in[22];
    const float* lo_b2  = (const float*)d_in[23];
    const float* lo_g2  = (const float*)d_in[24];
    const float* lo_bb2 = (const float*)d_in[25];

    float* out0 = (float*)d_out;                       // (B,C,11,11)
    float* tk   = out0 + (size_t)BDIM_B * CDIM * SS;   // (1,C,11,11,3,3)

    // workspace layout (bytes, 64B-aligned chunks)
    char* ws = (char*)d_ws;
    size_t off = 0;
    auto alloc = [&](size_t bytes) { void* p = ws + off; off += (bytes + 63) & ~(size_t)63; return p; };
    u16*   Xb      = (u16*)alloc((size_t)MROWS * 512 * 2);
    u16*   Y1      = (u16*)alloc((size_t)MROWS * 1024 * 2);
    u16*   w1b     = (u16*)alloc((size_t)W1N * 2);
    u16*   w2b     = (u16*)alloc((size_t)W2N * 2);
    u16*   lw1b    = (u16*)alloc((size_t)L1N * 2);
    u16*   lw2b    = (u16*)alloc((size_t)L2N * 2);
    u16*   asum_b  = (u16*)alloc((size_t)128 * 1024 * 2);   // rows 121..127 unwritten
    u16*   a3b     = (u16*)alloc((size_t)128 * 1024 * 2);
    u16*   ts_pc   = (u16*)alloc((size_t)128 * 512 * 2);    // task_s (p,c) bf16
    float* dctT    = (float*)alloc((size_t)SS * 512 * 4);
    u16*   wcb     = (u16*)alloc((size_t)WCN * 2);          // w_conv bf16 16x512 (pad)
    float* ckbuf   = (float*)alloc((size_t)BDIM_B * CDIM * KK * 4);
    float* skbuf   = (float*)alloc((size_t)BDIM_B * SS * KK * 4);
    float* ck_t    = (float*)alloc((size_t)CDIM * KK * 4);
    float* sk_t    = (float*)alloc((size_t)SS * KK * 4);

    // --- prep: x transpose + weight casts + dct transpose + w_conv pad ---
    hipLaunchKernelGGL(prep_combo, dim3(PREP_BLKS), dim3(256), 0, stream,
                       x, Xb, up_w1, up_w2, lo_w1, lo_w2, dct_w, w_conv,
                       w1b, w2b, lw1b, lw2b, dctT, wcb);

    // --- up path: two MFMA GEMMs (round-0 BK=64, M-chunk XCD swizzle) ---
    hipLaunchKernelGGL((gemm_mfma<1, 1>), dim3(121 * 8), dim3(256), 0, stream,
                       Xb, w1b, up_b1, up_g1, up_bb1, (void*)Y1, 512, 1024, 8);
    hipLaunchKernelGGL((gemm_mfma<2, 1>), dim3(121 * 8), dim3(256), 0, stream,
                       Y1, w2b, up_b2, up_g2, up_bb2, (void*)asum_b, 1024, 1024, 8);

    // --- lo path: barrier-free 32-col GEMMs (32 + 16 blocks) ---
    hipLaunchKernelGGL((gemm_small<3>), dim3(32), dim3(256), 0, stream,
                       asum_b, lw1b, lo_b1, lo_g1, lo_bb1, a3b, 1024, 1024);
    hipLaunchKernelGGL((gemm_small<4>), dim3(16), dim3(256), 0, stream,
                       a3b, lw2b, lo_b2, lo_g2, lo_bb2, ts_pc, 1024, 512);

    // --- spatial MFMA GEMM + channel chain, one 251-block dispatch ---
    hipLaunchKernelGGL(spatial_ck_combo, dim3(122 + 129), dim3(256), 0, stream,
                       Xb, ts_pc, wcb, b_conv, g_sp, b_sp,
                       dctT, fc1, fc2, g_ch, b_ch,
                       skbuf, sk_t, ckbuf, ck_t);

    // --- final fused + task-kernel write, one dispatch ---
    hipLaunchKernelGGL(final_combo, dim3(FIN_BLKS), dim3(256), 0, stream,
                       x, skbuf, sk_t, ckbuf, ck_t, out0, tk);
}